// Round 1
// baseline (287.507 us; speedup 1.0000x reference)
//
#include <hip/hip_runtime.h>
#include <stdint.h>

#define BATCH 32
#define SEQ   1024
#define DIM   64
#define NKT   (SEQ / 64)

typedef uint16_t u16;
typedef uint32_t u32;
typedef unsigned long long u64;
typedef __attribute__((ext_vector_type(8))) __bf16 bf16x8;
typedef __attribute__((ext_vector_type(4))) float  f32x4;
typedef __attribute__((ext_vector_type(4))) u32    u32x4;

__device__ __forceinline__ float fexp2(float x) {
#if __has_builtin(__builtin_amdgcn_exp2f)
    return __builtin_amdgcn_exp2f(x);
#else
    return exp2f(x);
#endif
}

__device__ __forceinline__ u16 f2bf(float f) {
    u32 x = __builtin_bit_cast(u32, f);
    x += 0x7FFFu + ((x >> 16) & 1u);   // round-to-nearest-even
    return (u16)(x >> 16);
}

// 8 contiguous f32 -> bf16x8 fragment (RNE)
__device__ __forceinline__ bf16x8 cvt8(const float* __restrict__ p) {
    f32x4 a = *reinterpret_cast<const f32x4*>(p);
    f32x4 b = *reinterpret_cast<const f32x4*>(p + 4);
    u16 t[8];
    t[0] = f2bf(a[0]); t[1] = f2bf(a[1]); t[2] = f2bf(a[2]); t[3] = f2bf(a[3]);
    t[4] = f2bf(b[0]); t[5] = f2bf(b[1]); t[6] = f2bf(b[2]); t[7] = f2bf(b[3]);
    return __builtin_bit_cast(bf16x8, *reinterpret_cast<u32x4*>(t));
}

// scaled variant (scale folded into the bf16 fragment)
__device__ __forceinline__ bf16x8 cvt8s(const float* __restrict__ p, float s) {
    f32x4 a = *reinterpret_cast<const f32x4*>(p);
    f32x4 b = *reinterpret_cast<const f32x4*>(p + 4);
    u16 t[8];
    t[0] = f2bf(a[0] * s); t[1] = f2bf(a[1] * s); t[2] = f2bf(a[2] * s); t[3] = f2bf(a[3] * s);
    t[4] = f2bf(b[0] * s); t[5] = f2bf(b[1] * s); t[6] = f2bf(b[2] * s); t[7] = f2bf(b[3] * s);
    return __builtin_bit_cast(bf16x8, *reinterpret_cast<u32x4*>(t));
}

__device__ __forceinline__ bf16x8 ldg8(const u16* p) {
    u32x4 u = *reinterpret_cast<const u32x4*>(p);
    return __builtin_bit_cast(bf16x8, u);
}

// spread 16 bits to every 4th bit position of a u64
__device__ __forceinline__ u64 spread4(u64 x) {
    x &= 0xFFFFull;
    x = (x | (x << 24)) & 0x000000FF000000FFull;
    x = (x | (x << 12)) & 0x000F000F000F000Full;
    x = (x | (x << 6))  & 0x0303030303030303ull;
    x = (x | (x << 3))  & 0x1111111111111111ull;
    return x;
}

// ---------------------------------------------------------------------------
// Kernel 1: V f32 [B][S][D] -> Vt bf16 [B][D][S]
// ---------------------------------------------------------------------------
__global__ __launch_bounds__(256) void vt_kernel(const float* __restrict__ v,
                                                 u16* __restrict__ vt) {
    __shared__ u16 tile[64][72];
    const int b  = blockIdx.y;
    const int k0 = blockIdx.x * 64;
    const int t  = threadIdx.x;
    const float* vb  = v  + (size_t)b * SEQ * DIM;
    u16*         vtb = vt + (size_t)b * DIM * SEQ;

    {
        int kk = t >> 2;
        int d0 = (t & 3) * 16;
        const float* src = vb + (size_t)(k0 + kk) * DIM + d0;
        u16 tmp[16];
#pragma unroll
        for (int i = 0; i < 4; ++i) {
            f32x4 a = *reinterpret_cast<const f32x4*>(src + i * 4);
            tmp[i * 4 + 0] = f2bf(a[0]); tmp[i * 4 + 1] = f2bf(a[1]);
            tmp[i * 4 + 2] = f2bf(a[2]); tmp[i * 4 + 3] = f2bf(a[3]);
        }
        *reinterpret_cast<u32x4*>(&tile[kk][d0])     = *reinterpret_cast<u32x4*>(tmp);
        *reinterpret_cast<u32x4*>(&tile[kk][d0 + 8]) = *reinterpret_cast<u32x4*>(tmp + 8);
    }
    __syncthreads();
#pragma unroll
    for (int i = 0; i < 2; ++i) {
        int d  = t / 8 + i * 32;
        int ks = (t % 8) * 8;
        u16 tmp[8];
#pragma unroll
        for (int j = 0; j < 8; ++j) tmp[j] = tile[ks + j][d];
        *reinterpret_cast<u32x4*>(vtb + (size_t)d * SEQ + k0 + ks) =
            *reinterpret_cast<u32x4*>(tmp);
    }
}

// ---------------------------------------------------------------------------
// Kernel 1b: K f32 -> bf16, row-major (direct B-fragment loads in attn)
// ---------------------------------------------------------------------------
__global__ __launch_bounds__(256) void kbf_kernel(const float* __restrict__ k,
                                                  u16* __restrict__ kb) {
    size_t i = ((size_t)blockIdx.x * 256 + threadIdx.x) * 8;
    bf16x8 v = cvt8(k + i);
    *reinterpret_cast<u32x4*>(kb + i) = __builtin_bit_cast(u32x4, v);
}

// ---------------------------------------------------------------------------
// Kernel 1c: mask int32 [B][S][S] -> bitmask u64 [B][S][S/64] (bit p = col p)
// Streaming: 16 B/lane loads, ballot-based 32x compression.
// ---------------------------------------------------------------------------
__global__ __launch_bounds__(256) void mpack_kernel(const int* __restrict__ m,
                                                    u64* __restrict__ bits) {
    const int wid  = blockIdx.x * 4 + (threadIdx.x >> 6);
    const int lane = threadIdx.x & 63;
    // 131072 groups of 256 ints; 8192 waves * 16 iters
#pragma unroll 1
    for (int it = 0; it < 16; ++it) {
        size_t g = (size_t)wid + (size_t)it * 8192;
        const int* p = m + g * 256 + lane * 4;
        u32x4 x = *reinterpret_cast<const u32x4*>(p);
        int nib = (x[0] != 0) | ((x[1] != 0) << 1) | ((x[2] != 0) << 2) | ((x[3] != 0) << 3);
        u64 b0 = __ballot(nib & 1);
        u64 b1 = __ballot(nib & 2);
        u64 b2 = __ballot(nib & 4);
        u64 b3 = __ballot(nib & 8);
        if (lane < 4) {
            int sh = lane * 16;
            u64 w = spread4(b0 >> sh)
                  | (spread4(b1 >> sh) << 1)
                  | (spread4(b2 >> sh) << 2)
                  | (spread4(b3 >> sh) << 3);
            bits[g * 4 + lane] = w;
        }
    }
}

// ---------------------------------------------------------------------------
// Kernel 2 (fast): fused rel-pos attention.
//  - K pre-converted bf16 (no inner-loop cvt), V via bf16 transpose,
//  - mask from bit-words (registers, prefetched one kt ahead, no LDS stage),
//  - scaling 0.125*log2(e) folded into Q fragments, exp2 softmax.
// ---------------------------------------------------------------------------
__global__ __launch_bounds__(256, 3) void attn_fast(
    const float* __restrict__ qg, const u16* __restrict__ kbf,
    const u16* __restrict__ vt, const u64* __restrict__ mbits,
    const float* __restrict__ ptg, float* __restrict__ outg) {
    __shared__ float qp[64][132];        // 33792 B (pre-scaled q . pos^T)
    __shared__ u16   plds[4][16][72];    //  9216 B, per-wave P tile

    const int b    = blockIdx.y;
    const int q0   = blockIdx.x * 64;
    const int tid  = threadIdx.x;
    const int wave = tid >> 6;
    const int lane = tid & 63;
    const int quad = lane >> 4;
    const int c16  = lane & 15;

    const float SC = 0.125f * 1.44269504088896340736f;  // 1/8 * log2(e)

    const float* qb = qg + ((size_t)b * SEQ + q0) * DIM;

    // Q A-fragments, pre-scaled (so S and qp are both in exp2 space)
    const bf16x8 qA0 = cvt8s(qb + (size_t)(wave * 16 + c16) * DIM + quad * 8, SC);
    const bf16x8 qA1 = cvt8s(qb + (size_t)(wave * 16 + c16) * DIM + 32 + quad * 8, SC);

    // qp[64][129] = (SC*Q)(64x64) . pos_table^T via MFMA
    for (int jt = 0; jt < 9; ++jt) {
        int j0 = jt * 16;
        int jr = min(j0 + c16, 128);
        bf16x8 b0 = cvt8(ptg + (size_t)jr * DIM + quad * 8);
        bf16x8 b1 = cvt8(ptg + (size_t)jr * DIM + 32 + quad * 8);
        f32x4 acc = {0.f, 0.f, 0.f, 0.f};
        acc = __builtin_amdgcn_mfma_f32_16x16x32_bf16(qA0, b0, acc, 0, 0, 0);
        acc = __builtin_amdgcn_mfma_f32_16x16x32_bf16(qA1, b1, acc, 0, 0, 0);
        int jcol = j0 + c16;
        if (jcol <= 128) {
#pragma unroll
            for (int r = 0; r < 4; ++r)
                qp[wave * 16 + quad * 4 + r][jcol] = acc[r];
        }
    }
    // per-wave LDS region; same-wave DS ordering is in-order -> no barrier

    const u16* kb_base  = kbf + (size_t)b * SEQ * DIM;
    const u16* vtb_base = vt  + (size_t)b * DIM * SEQ;
    const u64* mrow     = mbits + (size_t)(b * SEQ + q0 + wave * 16) * NKT;

    // current mask words for this lane's 4 rows (broadcast loads, L1-served)
    u64 w[4];
#pragma unroll
    for (int r = 0; r < 4; ++r) w[r] = mrow[(quad * 4 + r) * NKT];

    float m_run[4], l_run[4];
    f32x4 O[4];
#pragma unroll
    for (int r = 0; r < 4; ++r) { m_run[r] = -1e30f; l_run[r] = 0.f; }
#pragma unroll
    for (int d = 0; d < 4; ++d) O[d] = f32x4{0.f, 0.f, 0.f, 0.f};

#pragma unroll 1
    for (int kt = 0; kt < NKT; ++kt) {
        const int k0 = kt * 64;

        // prefetch next tile's mask words (hides the HBM/L2 latency under MFMA)
        u64 wn[4];
        const int ktn = (kt + 1) & (NKT - 1);
#pragma unroll
        for (int r = 0; r < 4; ++r) wn[r] = mrow[(quad * 4 + r) * NKT + ktn];

        // --- S = (SC*Q) . K^T, K fragments are direct bf16 16B loads --------
        f32x4 S[4];
#pragma unroll
        for (int sub = 0; sub < 4; ++sub) {
            const u16* kr = kb_base + (size_t)(k0 + sub * 16 + c16) * DIM;
            bf16x8 kf0 = ldg8(kr + quad * 8);
            bf16x8 kf1 = ldg8(kr + 32 + quad * 8);
            f32x4 acc = {0.f, 0.f, 0.f, 0.f};
            acc = __builtin_amdgcn_mfma_f32_16x16x32_bf16(qA0, kf0, acc, 0, 0, 0);
            acc = __builtin_amdgcn_mfma_f32_16x16x32_bf16(qA1, kf1, acc, 0, 0, 0);
            S[sub] = acc;
        }

        // --- logits (already scaled): + qp gather, mask bit -> -1e30 --------
        float sv[4][4];
#pragma unroll
        for (int r = 0; r < 4; ++r) {
            const int row_l = quad * 4 + r;
            const int row_g = q0 + wave * 16 + row_l;
            const u64 wr = w[r] >> c16;   // bit for col sub*16+c16 now at sub*16
#pragma unroll
            for (int sub = 0; sub < 4; ++sub) {
                int col_g = k0 + sub * 16 + c16;
                int rel = col_g - row_g;
                rel = rel < -64 ? -64 : (rel > 64 ? 64 : rel);
                float x = S[sub][r] + qp[wave * 16 + row_l][rel + 64];
                u32 bit = (u32)(wr >> (sub * 16)) & 1u;
                sv[sub][r] = bit ? -1e30f : x;
            }
        }

        // --- online softmax in exp2 space ----------------------------------
        float m_new[4], alpha[4];
#pragma unroll
        for (int r = 0; r < 4; ++r) {
            float rmax = fmaxf(fmaxf(sv[0][r], sv[1][r]), fmaxf(sv[2][r], sv[3][r]));
            rmax = fmaxf(rmax, __shfl_xor(rmax, 1));
            rmax = fmaxf(rmax, __shfl_xor(rmax, 2));
            rmax = fmaxf(rmax, __shfl_xor(rmax, 4));
            rmax = fmaxf(rmax, __shfl_xor(rmax, 8));
            m_new[r] = fmaxf(m_run[r], rmax);
            alpha[r] = fexp2(m_run[r] - m_new[r]);
            m_run[r] = m_new[r];
        }
#pragma unroll
        for (int r = 0; r < 4; ++r) {
            float rs = 0.f;
#pragma unroll
            for (int sub = 0; sub < 4; ++sub) {
                float e = fexp2(sv[sub][r] - m_new[r]);  // masked -> exp2(-huge)=0
                rs += e;
                plds[wave][quad * 4 + r][sub * 16 + c16] = f2bf(e);
            }
            rs += __shfl_xor(rs, 1);
            rs += __shfl_xor(rs, 2);
            rs += __shfl_xor(rs, 4);
            rs += __shfl_xor(rs, 8);
            l_run[r] = l_run[r] * alpha[r] + rs;
#pragma unroll
            for (int d = 0; d < 4; ++d) O[d][r] *= alpha[r];
        }

        // --- P (A-layout from LDS) and PV accumulate -----------------------
        bf16x8 pA0 = *reinterpret_cast<bf16x8*>(&plds[wave][c16][quad * 8]);
        bf16x8 pA1 = *reinterpret_cast<bf16x8*>(&plds[wave][c16][32 + quad * 8]);
#pragma unroll
        for (int d = 0; d < 4; ++d) {
            const u16* vr = vtb_base + (size_t)(d * 16 + c16) * SEQ + k0;
            bf16x8 vf0 = ldg8(vr + quad * 8);
            bf16x8 vf1 = ldg8(vr + 32 + quad * 8);
            O[d] = __builtin_amdgcn_mfma_f32_16x16x32_bf16(pA0, vf0, O[d], 0, 0, 0);
            O[d] = __builtin_amdgcn_mfma_f32_16x16x32_bf16(pA1, vf1, O[d], 0, 0, 0);
        }

#pragma unroll
        for (int r = 0; r < 4; ++r) w[r] = wn[r];
    }

    // --- epilogue: out = O / l, FLOAT32 ------------------------------------
    float* ob = outg + ((size_t)b * SEQ + q0) * DIM;
#pragma unroll
    for (int r = 0; r < 4; ++r) {
        float inv = 1.f / l_run[r];
        int row_l = wave * 16 + quad * 4 + r;
#pragma unroll
        for (int d = 0; d < 4; ++d)
            ob[(size_t)row_l * DIM + d * 16 + c16] = O[d][r] * inv;
    }
}

// ---------------------------------------------------------------------------
// Fallback kernel (previous version) for small workspace.
// ---------------------------------------------------------------------------
template <bool USE_VT>
__global__ __launch_bounds__(256, 2) void attn_kernel(
    const float* __restrict__ qg, const float* __restrict__ kg,
    const void* __restrict__ vgv, const int* __restrict__ maskg,
    const float* __restrict__ ptg, float* __restrict__ outg) {
    __shared__ float qp[64][132];
    __shared__ int   mlds[4][16][68];
    __shared__ u16   plds[4][16][72];

    const int b    = blockIdx.y;
    const int q0   = blockIdx.x * 64;
    const int tid  = threadIdx.x;
    const int wave = tid >> 6;
    const int lane = tid & 63;
    const int quad = lane >> 4;
    const int c16  = lane & 15;

    const float* qb = qg + ((size_t)b * SEQ + q0) * DIM;
    const float* kb = kg + (size_t)b * SEQ * DIM;
    const int*   mb = maskg + ((size_t)b * SEQ + q0) * SEQ;

    const bf16x8 qA0 = cvt8(qb + (size_t)(wave * 16 + c16) * DIM + quad * 8);
    const bf16x8 qA1 = cvt8(qb + (size_t)(wave * 16 + c16) * DIM + 32 + quad * 8);

    for (int jt = 0; jt < 9; ++jt) {
        int j0 = jt * 16;
        int jr = min(j0 + c16, 128);
        bf16x8 b0 = cvt8(ptg + (size_t)jr * DIM + quad * 8);
        bf16x8 b1 = cvt8(ptg + (size_t)jr * DIM + 32 + quad * 8);
        f32x4 acc = {0.f, 0.f, 0.f, 0.f};
        acc = __builtin_amdgcn_mfma_f32_16x16x32_bf16(qA0, b0, acc, 0, 0, 0);
        acc = __builtin_amdgcn_mfma_f32_16x16x32_bf16(qA1, b1, acc, 0, 0, 0);
        int jcol = j0 + c16;
        if (jcol <= 128) {
#pragma unroll
            for (int r = 0; r < 4; ++r)
                qp[wave * 16 + quad * 4 + r][jcol] = acc[r];
        }
    }

    float m_run[4], l_run[4];
    f32x4 O[4];
#pragma unroll
    for (int r = 0; r < 4; ++r) { m_run[r] = -1e30f; l_run[r] = 0.f; }
#pragma unroll
    for (int d = 0; d < 4; ++d) O[d] = f32x4{0.f, 0.f, 0.f, 0.f};

#pragma unroll 1
    for (int kt = 0; kt < NKT; ++kt) {
        const int k0 = kt * 64;
        {
            int row_l = lane >> 2;
            const int* mrow = mb + (size_t)(wave * 16 + row_l) * SEQ + k0;
#pragma unroll
            for (int i = 0; i < 4; ++i) {
                int seg = (lane & 3) + i * 4;
                *reinterpret_cast<u32x4*>(&mlds[wave][row_l][seg * 4]) =
                    *reinterpret_cast<const u32x4*>(mrow + seg * 4);
            }
        }

        f32x4 S[4];
#pragma unroll
        for (int sub = 0; sub < 4; ++sub) {
            const float* kr = kb + (size_t)(k0 + sub * 16 + c16) * DIM;
            bf16x8 kb0 = cvt8(kr + quad * 8);
            bf16x8 kb1 = cvt8(kr + 32 + quad * 8);
            f32x4 acc = {0.f, 0.f, 0.f, 0.f};
            acc = __builtin_amdgcn_mfma_f32_16x16x32_bf16(qA0, kb0, acc, 0, 0, 0);
            acc = __builtin_amdgcn_mfma_f32_16x16x32_bf16(qA1, kb1, acc, 0, 0, 0);
            S[sub] = acc;
        }

        float sv[4][4];
#pragma unroll
        for (int sub = 0; sub < 4; ++sub) {
#pragma unroll
            for (int r = 0; r < 4; ++r) {
                int row_l = quad * 4 + r;
                int row_g = q0 + wave * 16 + row_l;
                int col_g = k0 + sub * 16 + c16;
                int rel = col_g - row_g;
                rel = rel < -64 ? -64 : (rel > 64 ? 64 : rel);
                float x = (S[sub][r] + qp[wave * 16 + row_l][rel + 64]) * 0.125f;
                int mv = mlds[wave][row_l][sub * 16 + c16];
                sv[sub][r] = mv ? -1e30f : x;
            }
        }

        float m_new[4], alpha[4];
#pragma unroll
        for (int r = 0; r < 4; ++r) {
            float rmax = fmaxf(fmaxf(sv[0][r], sv[1][r]), fmaxf(sv[2][r], sv[3][r]));
            rmax = fmaxf(rmax, __shfl_xor(rmax, 1));
            rmax = fmaxf(rmax, __shfl_xor(rmax, 2));
            rmax = fmaxf(rmax, __shfl_xor(rmax, 4));
            rmax = fmaxf(rmax, __shfl_xor(rmax, 8));
            m_new[r] = fmaxf(m_run[r], rmax);
            alpha[r] = __expf(m_run[r] - m_new[r]);
            m_run[r] = m_new[r];
        }
#pragma unroll
        for (int r = 0; r < 4; ++r) {
            float rs = 0.f;
#pragma unroll
            for (int sub = 0; sub < 4; ++sub) {
                float e = __expf(sv[sub][r] - m_new[r]);
                rs += e;
                plds[wave][quad * 4 + r][sub * 16 + c16] = f2bf(e);
            }
            rs += __shfl_xor(rs, 1);
            rs += __shfl_xor(rs, 2);
            rs += __shfl_xor(rs, 4);
            rs += __shfl_xor(rs, 8);
            l_run[r] = l_run[r] * alpha[r] + rs;
#pragma unroll
            for (int d = 0; d < 4; ++d) O[d][r] *= alpha[r];
        }

        bf16x8 pA0 = *reinterpret_cast<bf16x8*>(&plds[wave][c16][quad * 8]);
        bf16x8 pA1 = *reinterpret_cast<bf16x8*>(&plds[wave][c16][32 + quad * 8]);
#pragma unroll
        for (int d = 0; d < 4; ++d) {
            bf16x8 vb0, vb1;
            if (USE_VT) {
                const u16* vtb = (const u16*)vgv + (size_t)b * DIM * SEQ +
                                 (size_t)(d * 16 + c16) * SEQ + k0;
                vb0 = ldg8(vtb + quad * 8);
                vb1 = ldg8(vtb + 32 + quad * 8);
            } else {
                u16 t0[8], t1[8];
                const float* vbase = (const float*)vgv +
                                     ((size_t)b * SEQ + k0) * DIM + d * 16 + c16;
#pragma unroll
                for (int j = 0; j < 8; ++j) {
                    t0[j] = f2bf(vbase[(size_t)(quad * 8 + j) * DIM]);
                    t1[j] = f2bf(vbase[(size_t)(32 + quad * 8 + j) * DIM]);
                }
                vb0 = __builtin_bit_cast(bf16x8, *reinterpret_cast<u32x4*>(t0));
                vb1 = __builtin_bit_cast(bf16x8, *reinterpret_cast<u32x4*>(t1));
            }
            O[d] = __builtin_amdgcn_mfma_f32_16x16x32_bf16(pA0, vb0, O[d], 0, 0, 0);
            O[d] = __builtin_amdgcn_mfma_f32_16x16x32_bf16(pA1, vb1, O[d], 0, 0, 0);
        }
    }

    float* ob = outg + ((size_t)b * SEQ + q0) * DIM;
#pragma unroll
    for (int r = 0; r < 4; ++r) {
        float inv = 1.f / l_run[r];
        int row_l = wave * 16 + quad * 4 + r;
#pragma unroll
        for (int d = 0; d < 4; ++d)
            ob[(size_t)row_l * DIM + d * 16 + c16] = O[d][r] * inv;
    }
}

// ---------------------------------------------------------------------------
extern "C" void kernel_launch(void* const* d_in, const int* in_sizes, int n_in,
                              void* d_out, int out_size, void* d_ws, size_t ws_size,
                              hipStream_t stream) {
    const float* q    = (const float*)d_in[0];
    const float* k    = (const float*)d_in[1];
    const float* v    = (const float*)d_in[2];
    const int*   mask = (const int*)d_in[3];
    const float* pt   = (const float*)d_in[4];
    float* out        = (float*)d_out;

    const size_t vt_bytes = (size_t)BATCH * SEQ * DIM * sizeof(u16);   // 4 MB
    const size_t kb_bytes = (size_t)BATCH * SEQ * DIM * sizeof(u16);   // 4 MB
    const size_t mb_bytes = (size_t)BATCH * SEQ * NKT * sizeof(u64);   // 4 MB
    dim3 grid(SEQ / 64, BATCH);

    if (ws_size >= vt_bytes + kb_bytes + mb_bytes) {
        u16* vt = (u16*)d_ws;
        u16* kb = (u16*)((char*)d_ws + vt_bytes);
        u64* mb2 = (u64*)((char*)d_ws + vt_bytes + kb_bytes);
        vt_kernel<<<grid, 256, 0, stream>>>(v, vt);
        kbf_kernel<<<dim3((BATCH * SEQ * DIM / 8) / 256), 256, 0, stream>>>(k, kb);
        mpack_kernel<<<dim3(2048), 256, 0, stream>>>(mask, mb2);
        attn_fast<<<grid, 256, 0, stream>>>(q, kb, vt, mb2, pt, out);
    } else if (ws_size >= vt_bytes) {
        u16* vt = (u16*)d_ws;
        vt_kernel<<<grid, 256, 0, stream>>>(v, vt);
        attn_kernel<true><<<grid, 256, 0, stream>>>(q, k, (const void*)vt, mask, pt, out);
    } else {
        attn_kernel<false><<<grid, 256, 0, stream>>>(q, k, (const void*)v, mask, pt, out);
    }
}

// Round 2
// 282.546 us; speedup vs baseline: 1.0176x; 1.0176x over previous
//
#include <hip/hip_runtime.h>
#include <stdint.h>

#define BATCH 32
#define SEQ   1024
#define DIM   64
#define NKT   (SEQ / 64)

typedef uint16_t u16;
typedef uint32_t u32;
typedef unsigned long long u64;
typedef __attribute__((ext_vector_type(8))) __bf16 bf16x8;
typedef __attribute__((ext_vector_type(4))) float  f32x4;
typedef __attribute__((ext_vector_type(4))) u32    u32x4;

__device__ __forceinline__ float fexp2(float x) {
#if __has_builtin(__builtin_amdgcn_exp2f)
    return __builtin_amdgcn_exp2f(x);
#else
    return exp2f(x);
#endif
}

__device__ __forceinline__ u16 f2bf(float f) {
    u32 x = __builtin_bit_cast(u32, f);
    x += 0x7FFFu + ((x >> 16) & 1u);   // round-to-nearest-even
    return (u16)(x >> 16);
}

// 8 contiguous f32 -> bf16x8 fragment (RNE)
__device__ __forceinline__ bf16x8 cvt8(const float* __restrict__ p) {
    f32x4 a = *reinterpret_cast<const f32x4*>(p);
    f32x4 b = *reinterpret_cast<const f32x4*>(p + 4);
    u16 t[8];
    t[0] = f2bf(a[0]); t[1] = f2bf(a[1]); t[2] = f2bf(a[2]); t[3] = f2bf(a[3]);
    t[4] = f2bf(b[0]); t[5] = f2bf(b[1]); t[6] = f2bf(b[2]); t[7] = f2bf(b[3]);
    return __builtin_bit_cast(bf16x8, *reinterpret_cast<u32x4*>(t));
}

// scaled variant (scale folded into the bf16 fragment)
__device__ __forceinline__ bf16x8 cvt8s(const float* __restrict__ p, float s) {
    f32x4 a = *reinterpret_cast<const f32x4*>(p);
    f32x4 b = *reinterpret_cast<const f32x4*>(p + 4);
    u16 t[8];
    t[0] = f2bf(a[0] * s); t[1] = f2bf(a[1] * s); t[2] = f2bf(a[2] * s); t[3] = f2bf(a[3] * s);
    t[4] = f2bf(b[0] * s); t[5] = f2bf(b[1] * s); t[6] = f2bf(b[2] * s); t[7] = f2bf(b[3] * s);
    return __builtin_bit_cast(bf16x8, *reinterpret_cast<u32x4*>(t));
}

__device__ __forceinline__ bf16x8 ldg8(const u16* p) {
    u32x4 u = *reinterpret_cast<const u32x4*>(p);
    return __builtin_bit_cast(bf16x8, u);
}

// ---------------------------------------------------------------------------
// Fused prepass:
//  - ALL 8192 blocks: mask int32 [B][S][S] -> ballot-native bitwords.
//    Layout: bits[((b*S+row)*4 + g)*4 + i], g = 256-col group, i = col%4.
//    Word i bit l = mask[row][g*256 + 4l + i]  (one ballot per word, no spread).
//  - blocks < 512 additionally: V f32 -> Vt bf16 [B][D][S] (LDS transpose)
//    and K f32 -> bf16 row-major.
// ---------------------------------------------------------------------------
__global__ __launch_bounds__(256) void prep_kernel(
    const float* __restrict__ kg, const float* __restrict__ vg,
    const int* __restrict__ mask, u16* __restrict__ kb,
    u16* __restrict__ vtb_, u64* __restrict__ bits) {
    __shared__ u16 tile[64][72];
    const int t    = threadIdx.x;
    const int wave = t >> 6;
    const int lane = t & 63;
    const int wid  = blockIdx.x * 4 + wave;   // 0..32767

    // ---- mask packing: 4 groups per wave, prefetched one ahead ------------
    u32x4 cur = *reinterpret_cast<const u32x4*>(
        mask + (size_t)(wid >> 2) * SEQ + (wid & 3) * 256 + lane * 4);
#pragma unroll 1
    for (int it = 0; it < 4; ++it) {
        const int rg = wid + it * 32768;
        u32x4 nxt;
        if (it < 3) {
            const int rg2 = wid + (it + 1) * 32768;
            nxt = *reinterpret_cast<const u32x4*>(
                mask + (size_t)(rg2 >> 2) * SEQ + (rg2 & 3) * 256 + lane * 4);
        }
        int nib = (cur[0] != 0) | ((cur[1] != 0) << 1) |
                  ((cur[2] != 0) << 2) | ((cur[3] != 0) << 3);
        u64 b0 = __ballot(nib & 1);
        u64 b1 = __ballot(nib & 2);
        u64 b2 = __ballot(nib & 4);
        u64 b3 = __ballot(nib & 8);
        if (lane < 4) {
            u64 w = (lane == 0) ? b0 : (lane == 1) ? b1 : (lane == 2) ? b2 : b3;
            bits[(size_t)rg * 4 + lane] = w;
        }
        cur = nxt;
    }

    // ---- V transpose + K bf16 for the first 512 blocks --------------------
    if (blockIdx.x < 512) {
        const int b  = blockIdx.x >> 4;
        const int k0 = (blockIdx.x & 15) * 64;

        // K f32 -> bf16 row-major (same 64x64 tile)
        {
            int kk = t >> 2;
            int d0 = (t & 3) * 16;
            const float* src = kg + ((size_t)b * SEQ + k0 + kk) * DIM + d0;
            u16 tmp[16];
#pragma unroll
            for (int i = 0; i < 4; ++i) {
                f32x4 a = *reinterpret_cast<const f32x4*>(src + i * 4);
                tmp[i * 4 + 0] = f2bf(a[0]); tmp[i * 4 + 1] = f2bf(a[1]);
                tmp[i * 4 + 2] = f2bf(a[2]); tmp[i * 4 + 3] = f2bf(a[3]);
            }
            u16* dst = kb + ((size_t)b * SEQ + k0 + kk) * DIM + d0;
            *reinterpret_cast<u32x4*>(dst)     = *reinterpret_cast<u32x4*>(tmp);
            *reinterpret_cast<u32x4*>(dst + 8) = *reinterpret_cast<u32x4*>(tmp + 8);
        }

        // V transpose via LDS
        const float* vb  = vg  + (size_t)b * SEQ * DIM;
        u16*         vtb = vtb_ + (size_t)b * DIM * SEQ;
        {
            int kk = t >> 2;
            int d0 = (t & 3) * 16;
            const float* src = vb + (size_t)(k0 + kk) * DIM + d0;
            u16 tmp[16];
#pragma unroll
            for (int i = 0; i < 4; ++i) {
                f32x4 a = *reinterpret_cast<const f32x4*>(src + i * 4);
                tmp[i * 4 + 0] = f2bf(a[0]); tmp[i * 4 + 1] = f2bf(a[1]);
                tmp[i * 4 + 2] = f2bf(a[2]); tmp[i * 4 + 3] = f2bf(a[3]);
            }
            *reinterpret_cast<u32x4*>(&tile[kk][d0])     = *reinterpret_cast<u32x4*>(tmp);
            *reinterpret_cast<u32x4*>(&tile[kk][d0 + 8]) = *reinterpret_cast<u32x4*>(tmp + 8);
        }
        __syncthreads();
#pragma unroll
        for (int i = 0; i < 2; ++i) {
            int d  = t / 8 + i * 32;
            int ks = (t % 8) * 8;
            u16 tmp[8];
#pragma unroll
            for (int j = 0; j < 8; ++j) tmp[j] = tile[ks + j][d];
            *reinterpret_cast<u32x4*>(vtb + (size_t)d * SEQ + k0 + ks) =
                *reinterpret_cast<u32x4*>(tmp);
        }
    }
}

// ---------------------------------------------------------------------------
// Fused rel-pos attention, split-K across wave pairs.
// 512 threads = 8 waves: wave (wq = w&3, wk = w>>2).
//   wq: q-row group (16 rows), wk: K-half (kt in [wk*8, wk*8+8)).
// 2 blocks/CU x 8 waves = 16 waves/CU (2x round-1 occupancy).
// Flash-merge of the two halves via LDS (overlaid on dead qp region).
// ---------------------------------------------------------------------------
__global__ __launch_bounds__(512, 4) void attn_fast2(
    const float* __restrict__ qg, const u16* __restrict__ kbf,
    const u16* __restrict__ vt, const u64* __restrict__ mbits,
    const float* __restrict__ ptg, float* __restrict__ outg) {
    __shared__ float qp[64][132];        // 33792 B; reused as combine buffer
    __shared__ u16   plds[8][16][72];    // 18432 B, per-wave P tile

    const int b    = blockIdx.y;
    const int q0   = blockIdx.x * 64;
    const int tid  = threadIdx.x;
    const int wave = tid >> 6;
    const int lane = tid & 63;
    const int wq   = wave & 3;
    const int wk   = wave >> 2;
    const int quad = lane >> 4;
    const int c16  = lane & 15;

    const float SC = 0.125f * 1.44269504088896340736f;  // 1/8 * log2(e)

    const float* qb = qg + ((size_t)b * SEQ + q0) * DIM;

    // Q A-fragments, pre-scaled (exp2 space)
    const bf16x8 qA0 = cvt8s(qb + (size_t)(wq * 16 + c16) * DIM + quad * 8, SC);
    const bf16x8 qA1 = cvt8s(qb + (size_t)(wq * 16 + c16) * DIM + 32 + quad * 8, SC);

    // mask bitwords for this wave's rows and its two 4-kt groups (8 loads, L2)
    const size_t rowbase = (size_t)b * SEQ + q0 + wq * 16 + quad * 4;
    u64 w2[2][4];
#pragma unroll
    for (int gg = 0; gg < 2; ++gg)
#pragma unroll
        for (int r = 0; r < 4; ++r)
            w2[gg][r] = mbits[((rowbase + r) * 4 + (wk * 2 + gg)) * 4 + (c16 & 3)];

    // qp[64][129] = (SC*Q)(64x64) . pos_table^T ; jt tiles split across wk
    {
        const int jt0 = wk ? 5 : 0, jt1 = wk ? 9 : 5;
        for (int jt = jt0; jt < jt1; ++jt) {
            int j0 = jt * 16;
            int jr = min(j0 + c16, 128);
            bf16x8 b0 = cvt8(ptg + (size_t)jr * DIM + quad * 8);
            bf16x8 b1 = cvt8(ptg + (size_t)jr * DIM + 32 + quad * 8);
            f32x4 acc = {0.f, 0.f, 0.f, 0.f};
            acc = __builtin_amdgcn_mfma_f32_16x16x32_bf16(qA0, b0, acc, 0, 0, 0);
            acc = __builtin_amdgcn_mfma_f32_16x16x32_bf16(qA1, b1, acc, 0, 0, 0);
            int jcol = j0 + c16;
            if (jcol <= 128) {
#pragma unroll
                for (int r = 0; r < 4; ++r)
                    qp[wq * 16 + quad * 4 + r][jcol] = acc[r];
            }
        }
    }
    __syncthreads();   // qp complete (both halves)

    const u16* kb_base  = kbf + (size_t)b * SEQ * DIM;
    const u16* vtb_base = vt  + (size_t)b * DIM * SEQ;

    float m_run[4], l_run[4];
    f32x4 O[4];
#pragma unroll
    for (int r = 0; r < 4; ++r) { m_run[r] = -1e30f; l_run[r] = 0.f; }
#pragma unroll
    for (int d = 0; d < 4; ++d) O[d] = f32x4{0.f, 0.f, 0.f, 0.f};

#pragma unroll
    for (int gg = 0; gg < 2; ++gg) {
#pragma unroll 1
        for (int t = 0; t < 4; ++t) {
            const int kt = wk * 8 + gg * 4 + t;
            const int k0 = kt * 64;

            // --- S = (SC*Q) . K^T (direct bf16 fragment loads) -------------
            f32x4 S[4];
            __builtin_amdgcn_s_setprio(1);
#pragma unroll
            for (int sub = 0; sub < 4; ++sub) {
                const u16* kr = kb_base + (size_t)(k0 + sub * 16 + c16) * DIM;
                bf16x8 kf0 = ldg8(kr + quad * 8);
                bf16x8 kf1 = ldg8(kr + 32 + quad * 8);
                f32x4 acc = {0.f, 0.f, 0.f, 0.f};
                acc = __builtin_amdgcn_mfma_f32_16x16x32_bf16(qA0, kf0, acc, 0, 0, 0);
                acc = __builtin_amdgcn_mfma_f32_16x16x32_bf16(qA1, kf1, acc, 0, 0, 0);
                S[sub] = acc;
            }
            __builtin_amdgcn_s_setprio(0);

            // --- logits: + qp gather, mask bit select ----------------------
            float sv[4][4];
#pragma unroll
            for (int r = 0; r < 4; ++r) {
                const int row_l = quad * 4 + r;
                const int row_g = q0 + wq * 16 + row_l;
                const u64 wr = w2[gg][r] >> (t * 16 + (c16 >> 2));
#pragma unroll
                for (int sub = 0; sub < 4; ++sub) {
                    int col_g = k0 + sub * 16 + c16;
                    int rel = col_g - row_g;
                    rel = rel < -64 ? -64 : (rel > 64 ? 64 : rel);
                    float x = S[sub][r] + qp[wq * 16 + row_l][rel + 64];
                    u32 bit = (u32)(wr >> (sub * 4)) & 1u;
                    sv[sub][r] = bit ? -1e30f : x;
                }
            }

            // --- online softmax (exp2 space), defer-rescale when flat ------
            float m_new[4];
            bool need = false;
#pragma unroll
            for (int r = 0; r < 4; ++r) {
                float rmax = fmaxf(fmaxf(sv[0][r], sv[1][r]), fmaxf(sv[2][r], sv[3][r]));
                rmax = fmaxf(rmax, __shfl_xor(rmax, 1));
                rmax = fmaxf(rmax, __shfl_xor(rmax, 2));
                rmax = fmaxf(rmax, __shfl_xor(rmax, 4));
                rmax = fmaxf(rmax, __shfl_xor(rmax, 8));
                m_new[r] = fmaxf(m_run[r], rmax);
                need |= (m_new[r] > m_run[r]);
            }
            if (__any(need)) {
#pragma unroll
                for (int r = 0; r < 4; ++r) {
                    float alpha = fexp2(m_run[r] - m_new[r]);
                    l_run[r] *= alpha;
#pragma unroll
                    for (int d = 0; d < 4; ++d) O[d][r] *= alpha;
                }
            }
#pragma unroll
            for (int r = 0; r < 4; ++r) {
                m_run[r] = m_new[r];
                float rs = 0.f;
#pragma unroll
                for (int sub = 0; sub < 4; ++sub) {
                    float e = fexp2(sv[sub][r] - m_new[r]);  // masked -> 0
                    rs += e;
                    plds[wave][quad * 4 + r][sub * 16 + c16] = f2bf(e);
                }
                rs += __shfl_xor(rs, 1);
                rs += __shfl_xor(rs, 2);
                rs += __shfl_xor(rs, 4);
                rs += __shfl_xor(rs, 8);
                l_run[r] += rs;
            }

            // --- P (A-layout from per-wave LDS) and PV accumulate ----------
            bf16x8 pA0 = *reinterpret_cast<bf16x8*>(&plds[wave][c16][quad * 8]);
            bf16x8 pA1 = *reinterpret_cast<bf16x8*>(&plds[wave][c16][32 + quad * 8]);
            __builtin_amdgcn_s_setprio(1);
#pragma unroll
            for (int d = 0; d < 4; ++d) {
                const u16* vr = vtb_base + (size_t)(d * 16 + c16) * SEQ + k0;
                bf16x8 vf0 = ldg8(vr + quad * 8);
                bf16x8 vf1 = ldg8(vr + 32 + quad * 8);
                O[d] = __builtin_amdgcn_mfma_f32_16x16x32_bf16(pA0, vf0, O[d], 0, 0, 0);
                O[d] = __builtin_amdgcn_mfma_f32_16x16x32_bf16(pA1, vf1, O[d], 0, 0, 0);
            }
            __builtin_amdgcn_s_setprio(0);
        }
    }

    // --- flash-merge the two K-halves (combine buffer overlays dead qp) ----
    __syncthreads();   // everyone done reading qp
    float* cmb = &qp[0][0];
    const int cbase = (wq * 64 + lane) * 24;
    if (wk == 1) {
#pragma unroll
        for (int r = 0; r < 4; ++r) {
            cmb[cbase + r]     = m_run[r];
            cmb[cbase + 4 + r] = l_run[r];
        }
#pragma unroll
        for (int d = 0; d < 4; ++d)
#pragma unroll
            for (int r = 0; r < 4; ++r)
                cmb[cbase + 8 + d * 4 + r] = O[d][r];
    }
    __syncthreads();
    if (wk == 0) {
        float* ob = outg + ((size_t)b * SEQ + q0) * DIM;
#pragma unroll
        for (int r = 0; r < 4; ++r) {
            float m1 = cmb[cbase + r];
            float l1 = cmb[cbase + 4 + r];
            float mm = fmaxf(m_run[r], m1);
            float a0 = fexp2(m_run[r] - mm);
            float a1 = fexp2(m1 - mm);
            float inv = 1.f / (l_run[r] * a0 + l1 * a1);
            int row_l = wq * 16 + quad * 4 + r;
#pragma unroll
            for (int d = 0; d < 4; ++d) {
                float o = O[d][r] * a0 + cmb[cbase + 8 + d * 4 + r] * a1;
                ob[(size_t)row_l * DIM + d * 16 + c16] = o * inv;
            }
        }
    }
}

// ---------------------------------------------------------------------------
// Fallback path kernels (workspace too small for the fast path).
// ---------------------------------------------------------------------------
__global__ __launch_bounds__(256) void vt_kernel(const float* __restrict__ v,
                                                 u16* __restrict__ vt) {
    __shared__ u16 tile[64][72];
    const int b  = blockIdx.y;
    const int k0 = blockIdx.x * 64;
    const int t  = threadIdx.x;
    const float* vb  = v  + (size_t)b * SEQ * DIM;
    u16*         vtb = vt + (size_t)b * DIM * SEQ;

    {
        int kk = t >> 2;
        int d0 = (t & 3) * 16;
        const float* src = vb + (size_t)(k0 + kk) * DIM + d0;
        u16 tmp[16];
#pragma unroll
        for (int i = 0; i < 4; ++i) {
            f32x4 a = *reinterpret_cast<const f32x4*>(src + i * 4);
            tmp[i * 4 + 0] = f2bf(a[0]); tmp[i * 4 + 1] = f2bf(a[1]);
            tmp[i * 4 + 2] = f2bf(a[2]); tmp[i * 4 + 3] = f2bf(a[3]);
        }
        *reinterpret_cast<u32x4*>(&tile[kk][d0])     = *reinterpret_cast<u32x4*>(tmp);
        *reinterpret_cast<u32x4*>(&tile[kk][d0 + 8]) = *reinterpret_cast<u32x4*>(tmp + 8);
    }
    __syncthreads();
#pragma unroll
    for (int i = 0; i < 2; ++i) {
        int d  = t / 8 + i * 32;
        int ks = (t % 8) * 8;
        u16 tmp[8];
#pragma unroll
        for (int j = 0; j < 8; ++j) tmp[j] = tile[ks + j][d];
        *reinterpret_cast<u32x4*>(vtb + (size_t)d * SEQ + k0 + ks) =
            *reinterpret_cast<u32x4*>(tmp);
    }
}

template <bool USE_VT>
__global__ __launch_bounds__(256, 2) void attn_kernel(
    const float* __restrict__ qg, const float* __restrict__ kg,
    const void* __restrict__ vgv, const int* __restrict__ maskg,
    const float* __restrict__ ptg, float* __restrict__ outg) {
    __shared__ float qp[64][132];
    __shared__ int   mlds[4][16][68];
    __shared__ u16   plds[4][16][72];

    const int b    = blockIdx.y;
    const int q0   = blockIdx.x * 64;
    const int tid  = threadIdx.x;
    const int wave = tid >> 6;
    const int lane = tid & 63;
    const int quad = lane >> 4;
    const int c16  = lane & 15;

    const float* qb = qg + ((size_t)b * SEQ + q0) * DIM;
    const float* kb = kg + (size_t)b * SEQ * DIM;
    const int*   mb = maskg + ((size_t)b * SEQ + q0) * SEQ;

    const bf16x8 qA0 = cvt8(qb + (size_t)(wave * 16 + c16) * DIM + quad * 8);
    const bf16x8 qA1 = cvt8(qb + (size_t)(wave * 16 + c16) * DIM + 32 + quad * 8);

    for (int jt = 0; jt < 9; ++jt) {
        int j0 = jt * 16;
        int jr = min(j0 + c16, 128);
        bf16x8 b0 = cvt8(ptg + (size_t)jr * DIM + quad * 8);
        bf16x8 b1 = cvt8(ptg + (size_t)jr * DIM + 32 + quad * 8);
        f32x4 acc = {0.f, 0.f, 0.f, 0.f};
        acc = __builtin_amdgcn_mfma_f32_16x16x32_bf16(qA0, b0, acc, 0, 0, 0);
        acc = __builtin_amdgcn_mfma_f32_16x16x32_bf16(qA1, b1, acc, 0, 0, 0);
        int jcol = j0 + c16;
        if (jcol <= 128) {
#pragma unroll
            for (int r = 0; r < 4; ++r)
                qp[wave * 16 + quad * 4 + r][jcol] = acc[r];
        }
    }

    float m_run[4], l_run[4];
    f32x4 O[4];
#pragma unroll
    for (int r = 0; r < 4; ++r) { m_run[r] = -1e30f; l_run[r] = 0.f; }
#pragma unroll
    for (int d = 0; d < 4; ++d) O[d] = f32x4{0.f, 0.f, 0.f, 0.f};

#pragma unroll 1
    for (int kt = 0; kt < NKT; ++kt) {
        const int k0 = kt * 64;
        {
            int row_l = lane >> 2;
            const int* mrow = mb + (size_t)(wave * 16 + row_l) * SEQ + k0;
#pragma unroll
            for (int i = 0; i < 4; ++i) {
                int seg = (lane & 3) + i * 4;
                *reinterpret_cast<u32x4*>(&mlds[wave][row_l][seg * 4]) =
                    *reinterpret_cast<const u32x4*>(mrow + seg * 4);
            }
        }

        f32x4 S[4];
#pragma unroll
        for (int sub = 0; sub < 4; ++sub) {
            const float* kr = kb + (size_t)(k0 + sub * 16 + c16) * DIM;
            bf16x8 kb0 = cvt8(kr + quad * 8);
            bf16x8 kb1 = cvt8(kr + 32 + quad * 8);
            f32x4 acc = {0.f, 0.f, 0.f, 0.f};
            acc = __builtin_amdgcn_mfma_f32_16x16x32_bf16(qA0, kb0, acc, 0, 0, 0);
            acc = __builtin_amdgcn_mfma_f32_16x16x32_bf16(qA1, kb1, acc, 0, 0, 0);
            S[sub] = acc;
        }

        float sv[4][4];
#pragma unroll
        for (int sub = 0; sub < 4; ++sub) {
#pragma unroll
            for (int r = 0; r < 4; ++r) {
                int row_l = quad * 4 + r;
                int row_g = q0 + wave * 16 + row_l;
                int col_g = k0 + sub * 16 + c16;
                int rel = col_g - row_g;
                rel = rel < -64 ? -64 : (rel > 64 ? 64 : rel);
                float x = (S[sub][r] + qp[wave * 16 + row_l][rel + 64]) * 0.125f;
                int mv = mlds[wave][row_l][sub * 16 + c16];
                sv[sub][r] = mv ? -1e30f : x;
            }
        }

        float m_new[4], alpha[4];
#pragma unroll
        for (int r = 0; r < 4; ++r) {
            float rmax = fmaxf(fmaxf(sv[0][r], sv[1][r]), fmaxf(sv[2][r], sv[3][r]));
            rmax = fmaxf(rmax, __shfl_xor(rmax, 1));
            rmax = fmaxf(rmax, __shfl_xor(rmax, 2));
            rmax = fmaxf(rmax, __shfl_xor(rmax, 4));
            rmax = fmaxf(rmax, __shfl_xor(rmax, 8));
            m_new[r] = fmaxf(m_run[r], rmax);
            alpha[r] = __expf(m_run[r] - m_new[r]);
            m_run[r] = m_new[r];
        }
#pragma unroll
        for (int r = 0; r < 4; ++r) {
            float rs = 0.f;
#pragma unroll
            for (int sub = 0; sub < 4; ++sub) {
                float e = __expf(sv[sub][r] - m_new[r]);
                rs += e;
                plds[wave][quad * 4 + r][sub * 16 + c16] = f2bf(e);
            }
            rs += __shfl_xor(rs, 1);
            rs += __shfl_xor(rs, 2);
            rs += __shfl_xor(rs, 4);
            rs += __shfl_xor(rs, 8);
            l_run[r] = l_run[r] * alpha[r] + rs;
#pragma unroll
            for (int d = 0; d < 4; ++d) O[d][r] *= alpha[r];
        }

        bf16x8 pA0 = *reinterpret_cast<bf16x8*>(&plds[wave][c16][quad * 8]);
        bf16x8 pA1 = *reinterpret_cast<bf16x8*>(&plds[wave][c16][32 + quad * 8]);
#pragma unroll
        for (int d = 0; d < 4; ++d) {
            bf16x8 vb0, vb1;
            if (USE_VT) {
                const u16* vtb = (const u16*)vgv + (size_t)b * DIM * SEQ +
                                 (size_t)(d * 16 + c16) * SEQ + k0;
                vb0 = ldg8(vtb + quad * 8);
                vb1 = ldg8(vtb + 32 + quad * 8);
            } else {
                u16 t0[8], t1[8];
                const float* vbase = (const float*)vgv +
                                     ((size_t)b * SEQ + k0) * DIM + d * 16 + c16;
#pragma unroll
                for (int j = 0; j < 8; ++j) {
                    t0[j] = f2bf(vbase[(size_t)(quad * 8 + j) * DIM]);
                    t1[j] = f2bf(vbase[(size_t)(32 + quad * 8 + j) * DIM]);
                }
                vb0 = __builtin_bit_cast(bf16x8, *reinterpret_cast<u32x4*>(t0));
                vb1 = __builtin_bit_cast(bf16x8, *reinterpret_cast<u32x4*>(t1));
            }
            O[d] = __builtin_amdgcn_mfma_f32_16x16x32_bf16(pA0, vb0, O[d], 0, 0, 0);
            O[d] = __builtin_amdgcn_mfma_f32_16x16x32_bf16(pA1, vb1, O[d], 0, 0, 0);
        }
    }

    float* ob = outg + ((size_t)b * SEQ + q0) * DIM;
#pragma unroll
    for (int r = 0; r < 4; ++r) {
        float inv = 1.f / l_run[r];
        int row_l = wave * 16 + quad * 4 + r;
#pragma unroll
        for (int d = 0; d < 4; ++d)
            ob[(size_t)row_l * DIM + d * 16 + c16] = O[d][r] * inv;
    }
}

// ---------------------------------------------------------------------------
extern "C" void kernel_launch(void* const* d_in, const int* in_sizes, int n_in,
                              void* d_out, int out_size, void* d_ws, size_t ws_size,
                              hipStream_t stream) {
    const float* q    = (const float*)d_in[0];
    const float* k    = (const float*)d_in[1];
    const float* v    = (const float*)d_in[2];
    const int*   mask = (const int*)d_in[3];
    const float* pt   = (const float*)d_in[4];
    float* out        = (float*)d_out;

    const size_t vt_bytes = (size_t)BATCH * SEQ * DIM * sizeof(u16);   // 4 MB
    const size_t kb_bytes = (size_t)BATCH * SEQ * DIM * sizeof(u16);   // 4 MB
    const size_t mb_bytes = (size_t)BATCH * SEQ * 16 * sizeof(u64);    // 4 MB
    dim3 grid(SEQ / 64, BATCH);

    if (ws_size >= vt_bytes + kb_bytes + mb_bytes) {
        u16* vt  = (u16*)d_ws;
        u16* kb  = (u16*)((char*)d_ws + vt_bytes);
        u64* mb2 = (u64*)((char*)d_ws + vt_bytes + kb_bytes);
        prep_kernel<<<dim3(8192), 256, 0, stream>>>(k, v, mask, kb, vt, mb2);
        attn_fast2<<<grid, 512, 0, stream>>>(q, kb, vt, mb2, pt, out);
    } else if (ws_size >= vt_bytes) {
        u16* vt = (u16*)d_ws;
        vt_kernel<<<grid, 256, 0, stream>>>(v, vt);
        attn_kernel<true><<<grid, 256, 0, stream>>>(q, k, (const void*)vt, mask, pt, out);
    } else {
        attn_kernel<false><<<grid, 256, 0, stream>>>(q, k, (const void*)v, mask, pt, out);
    }
}